// Round 1
// baseline (170.100 us; speedup 1.0000x reference)
//
#include <hip/hip_runtime.h>
#include <hip/hip_bf16.h>
#include <stdint.h>

#define N_SPK 2048
#define UU 32
#define DD 256
#define HALF_U 16
#define M_ROWS (N_SPK * HALF_U)   // 32768 test rows

#define BM 128
#define BN 128
#define BK 64

typedef __attribute__((ext_vector_type(8))) short short8;   // 8 bf16 = 4 VGPRs
typedef __attribute__((ext_vector_type(4))) float f32x4;

typedef const __attribute__((address_space(1))) void ga_void;
typedef __attribute__((address_space(3))) void ls_void;

__device__ __forceinline__ void gld16(const void* g, void* l) {
    // width-16 async global->LDS (HW: LDS dest = wave-uniform base + lane*16)
    __builtin_amdgcn_global_load_lds((ga_void*)(uintptr_t)g,
                                     (ls_void*)(uintptr_t)l, 16, 0, 0);
}

__device__ __forceinline__ unsigned short f2bf(float x) {
    union { float f; unsigned u; } c; c.f = x;
    unsigned r = c.u + 0x7fffu + ((c.u >> 16) & 1u);  // RNE, no NaN inputs
    return (unsigned short)(r >> 16);
}

// ---------------- prep: centroids + normalization -> bf16 ----------------
// one wave per output row. tasks [0,32768): test rows; [32768,34816): centroids.
__global__ __launch_bounds__(256) void prep_kernel(const float* __restrict__ emb,
                                                   unsigned short* __restrict__ tn,
                                                   unsigned short* __restrict__ cn)
{
    const int w = threadIdx.x >> 6;
    const int l = threadIdx.x & 63;
    const int task = blockIdx.x * 4 + w;

    float4 v;
    if (task < M_ROWS) {
        const int m = task >> 4;
        const int t = task & 15;
        const size_t grow = (size_t)m * UU + HALF_U + t;
        v = *(const float4*)(emb + grow * DD + 4 * l);
    } else {
        const int n = task - M_ROWS;
        float ax = 0.f, ay = 0.f, az = 0.f, aw = 0.f;
        const float* base = emb + (size_t)n * UU * DD + 4 * l;
        #pragma unroll
        for (int j = 0; j < HALF_U; ++j) {
            float4 e = *(const float4*)(base + j * DD);
            ax += e.x; ay += e.y; az += e.z; aw += e.w;
        }
        const float inv = 1.0f / 16.0f;
        v = make_float4(ax * inv, ay * inv, az * inv, aw * inv);
    }
    float ss = v.x * v.x + v.y * v.y + v.z * v.z + v.w * v.w;
    #pragma unroll
    for (int d = 1; d < 64; d <<= 1) ss += __shfl_xor(ss, d);
    const float sc = 1.0f / fmaxf(sqrtf(ss), 1e-8f);

    ushort4 o;
    o.x = f2bf(v.x * sc); o.y = f2bf(v.y * sc);
    o.z = f2bf(v.z * sc); o.w = f2bf(v.w * sc);
    unsigned short* dst = (task < M_ROWS)
        ? (tn + (size_t)task * DD + 4 * l)
        : (cn + (size_t)(task - M_ROWS) * DD + 4 * l);
    *(ushort4*)dst = o;
}

// ---------------- staging: global -> LDS, inverse-XOR-swizzled source -----
__device__ __forceinline__ void stage_tiles(const char* gA, const char* gB,
                                            char* ldsA, char* ldsB,
                                            int k0b, int w, int l)
{
    #pragma unroll
    for (int i = 0; i < 4; ++i) {
        const int off = (w * 4 + i) * 1024 + l * 16;   // linear LDS byte offset
        const int row = off >> 7;                      // 0..127 (128B rows)
        const int sc  = ((off >> 4) & 7) ^ (row & 7);  // inverse swizzle (involution)
        const int goff = row * 512 + k0b + sc * 16;    // global row stride = 512B (K=256 bf16)
        gld16(gA + goff, ldsA + off);
        gld16(gB + goff, ldsB + off);
    }
}

__device__ __forceinline__ void compute_step(const char* Asb, const char* Bsb,
                                             f32x4 (&acc)[4][4],
                                             int wr, int wc, int r16, int hi)
{
    #pragma unroll
    for (int kk = 0; kk < 2; ++kk) {
        short8 a[4], b[4];
        #pragma unroll
        for (int mi = 0; mi < 4; ++mi) {
            const int row = wr * 64 + mi * 16 + r16;
            const int c16 = (kk * 4 + hi) ^ (row & 7);   // swizzled read
            a[mi] = *(const short8*)(Asb + row * 128 + c16 * 16);
        }
        #pragma unroll
        for (int ni = 0; ni < 4; ++ni) {
            const int row = wc * 64 + ni * 16 + r16;
            const int c16 = (kk * 4 + hi) ^ (row & 7);
            b[ni] = *(const short8*)(Bsb + row * 128 + c16 * 16);
        }
        #pragma unroll
        for (int mi = 0; mi < 4; ++mi)
            #pragma unroll
            for (int ni = 0; ni < 4; ++ni)
                acc[mi][ni] = __builtin_amdgcn_mfma_f32_16x16x32_bf16(
                    a[mi], b[ni], acc[mi][ni], 0, 0, 0);
    }
}

// ---------------- fused GEMM + exp + column-sum + diagonal ----------------
__global__ __launch_bounds__(256) void gemm_kernel(const unsigned short* __restrict__ tnb,
                                                   const unsigned short* __restrict__ cnb,
                                                   const float* __restrict__ alphaP,
                                                   const float* __restrict__ betaP,
                                                   float* __restrict__ total,
                                                   float* __restrict__ pos)
{
    __shared__ __align__(16) char As[2][BM * BK * 2];
    __shared__ __align__(16) char Bs[2][BN * BK * 2];
    __shared__ float colsum[BN];

    const int tid = threadIdx.x;
    const int l = tid & 63;
    const int w = tid >> 6;
    const int wr = w >> 1, wc = w & 1;
    const int r16 = l & 15, hi = l >> 4;
    const int bn = blockIdx.x;
    const int bm = blockIdx.y;

    const char* gA = (const char*)tnb + (size_t)bm * BM * 512;
    const char* gB = (const char*)cnb + (size_t)bn * BN * 512;

    f32x4 acc[4][4] = {};

    stage_tiles(gA, gB, As[0], Bs[0], 0, w, l);
    if (tid < BN) colsum[tid] = 0.0f;
    __syncthreads();   // drains vmcnt(0): buf0 staged

    int buf = 0;
    #pragma unroll
    for (int kt = 0; kt < 4; ++kt) {           // K = 256 = 4 * BK
        if (kt < 3) stage_tiles(gA, gB, As[buf ^ 1], Bs[buf ^ 1], (kt + 1) * BK * 2, w, l);
        compute_step(As[buf], Bs[buf], acc, wr, wc, r16, hi);
        __syncthreads();                       // full drain: next buf staged, this buf free
        buf ^= 1;
    }

    const float alpha = *alphaP;
    const float beta  = *betaP;

    #pragma unroll
    for (int ni = 0; ni < 4; ++ni) {
        const int colg = bn * BN + wc * 64 + ni * 16 + r16;   // C/D: col = lane&15
        float csum = 0.f;
        #pragma unroll
        for (int mi = 0; mi < 4; ++mi) {
            const int rowbase = bm * BM + wr * 64 + mi * 16 + hi * 4;  // row = (l>>4)*4+r
            #pragma unroll
            for (int r = 0; r < 4; ++r) {
                const float e = __expf(alpha * acc[mi][ni][r] + beta);
                csum += e;
                if (((rowbase + r) >> 4) == colg)     // positive pair: speaker == col
                    atomicAdd(pos + colg, e);
            }
        }
        csum += __shfl_xor(csum, 16);
        csum += __shfl_xor(csum, 32);
        if (hi == 0) atomicAdd(&colsum[wc * 64 + ni * 16 + r16], csum);
    }
    __syncthreads();
    if (tid < BN) atomicAdd(total + bn * BN + tid, colsum[tid]);
}

// ---------------- finalize: loss = mean(log(tot-pos) - log(pos)) ----------
__global__ __launch_bounds__(256) void finalize_kernel(const float* __restrict__ total,
                                                       const float* __restrict__ pos,
                                                       float* __restrict__ out)
{
    const int tid = threadIdx.x;
    float s = 0.f;
    for (int i = tid; i < N_SPK; i += 256) {
        const float p = pos[i];
        const float t = total[i];
        s += logf(t - p) - logf(p);
    }
    #pragma unroll
    for (int d = 1; d < 64; d <<= 1) s += __shfl_xor(s, d);
    __shared__ float wsum[4];
    if ((tid & 63) == 0) wsum[tid >> 6] = s;
    __syncthreads();
    if (tid == 0) out[0] = (wsum[0] + wsum[1] + wsum[2] + wsum[3]) * (1.0f / (float)N_SPK);
}

extern "C" void kernel_launch(void* const* d_in, const int* in_sizes, int n_in,
                              void* d_out, int out_size, void* d_ws, size_t ws_size,
                              hipStream_t stream)
{
    const float* emb    = (const float*)d_in[0];
    const float* alphaP = (const float*)d_in[2];
    const float* betaP  = (const float*)d_in[3];
    float* out = (float*)d_out;

    char* ws = (char*)d_ws;
    unsigned short* tn = (unsigned short*)ws;                       // 32768*256*2 = 16 MiB
    unsigned short* cn = (unsigned short*)(ws + 16777216);          // 2048*256*2  = 1 MiB
    float* total       = (float*)(ws + 16777216 + 1048576);         // 2048 f32
    float* pos         = total + N_SPK;                             // 2048 f32

    hipMemsetAsync(total, 0, 2 * N_SPK * sizeof(float), stream);

    hipLaunchKernelGGL(prep_kernel, dim3((M_ROWS + N_SPK) / 4), dim3(256), 0, stream,
                       emb, tn, cn);
    hipLaunchKernelGGL(gemm_kernel, dim3(N_SPK / BN, M_ROWS / BM), dim3(256), 0, stream,
                       tn, cn, alphaP, betaP, total, pos);
    hipLaunchKernelGGL(finalize_kernel, dim3(1), dim3(256), 0, stream,
                       total, pos, out);
}

// Round 2
// 159.463 us; speedup vs baseline: 1.0667x; 1.0667x over previous
//
#include <hip/hip_runtime.h>
#include <hip/hip_bf16.h>
#include <stdint.h>

#define N_SPK 2048
#define UU 32
#define DD 256
#define HALF_U 16
#define M_ROWS (N_SPK * HALF_U)   // 32768 test rows

// 256x256 tile, 8 waves (2M x 4N), BK=64, K=256 fully unrolled, counted vmcnt
#define BM 256
#define BN 256
#define BK 64

typedef __attribute__((ext_vector_type(8))) short short8;   // 8 bf16 = 4 VGPRs
typedef __attribute__((ext_vector_type(4))) float f32x4;

typedef const __attribute__((address_space(1))) void ga_void;
typedef __attribute__((address_space(3))) void ls_void;

__device__ __forceinline__ void gld16(const void* g, void* l) {
    __builtin_amdgcn_global_load_lds((ga_void*)(uintptr_t)g,
                                     (ls_void*)(uintptr_t)l, 16, 0, 0);
}

__device__ __forceinline__ unsigned short f2bf(float x) {
    union { float f; unsigned u; } c; c.f = x;
    unsigned r = c.u + 0x7fffu + ((c.u >> 16) & 1u);  // RNE, no NaN inputs
    return (unsigned short)(r >> 16);
}

// ---------------- prep: centroids + normalization -> bf16 ----------------
__global__ __launch_bounds__(256) void prep_kernel(const float* __restrict__ emb,
                                                   unsigned short* __restrict__ tn,
                                                   unsigned short* __restrict__ cn)
{
    const int w = threadIdx.x >> 6;
    const int l = threadIdx.x & 63;
    const int task = blockIdx.x * 4 + w;

    float4 v;
    if (task < M_ROWS) {
        const int m = task >> 4;
        const int t = task & 15;
        const size_t grow = (size_t)m * UU + HALF_U + t;
        v = *(const float4*)(emb + grow * DD + 4 * l);
    } else {
        const int n = task - M_ROWS;
        float ax = 0.f, ay = 0.f, az = 0.f, aw = 0.f;
        const float* base = emb + (size_t)n * UU * DD + 4 * l;
        #pragma unroll
        for (int j = 0; j < HALF_U; ++j) {
            float4 e = *(const float4*)(base + j * DD);
            ax += e.x; ay += e.y; az += e.z; aw += e.w;
        }
        const float inv = 1.0f / 16.0f;
        v = make_float4(ax * inv, ay * inv, az * inv, aw * inv);
    }
    float ss = v.x * v.x + v.y * v.y + v.z * v.z + v.w * v.w;
    #pragma unroll
    for (int d = 1; d < 64; d <<= 1) ss += __shfl_xor(ss, d);
    const float sc = 1.0f / fmaxf(sqrtf(ss), 1e-8f);

    ushort4 o;
    o.x = f2bf(v.x * sc); o.y = f2bf(v.y * sc);
    o.z = f2bf(v.z * sc); o.w = f2bf(v.w * sc);
    unsigned short* dst = (task < M_ROWS)
        ? (tn + (size_t)task * DD + 4 * l)
        : (cn + (size_t)(task - M_ROWS) * DD + 4 * l);
    *(ushort4*)dst = o;
}

// ---------------- staging: one 256x64 K-tile of one matrix pair ----------
// LDS layout: [256 rows][64 bf16 = 128B], 16B granule c16 ^= (row&7).
// global_load_lds writes LDS linearly (base+lane*16); so the XOR is applied
// to the GLOBAL source address (inverse==same involution), and again on read.
__device__ __forceinline__ void stage_kt(const char* gA, const char* gB,
                                         char* lA, char* lB, int ktb, int tid)
{
    #pragma unroll
    for (int i = 0; i < 4; ++i) {
        const int off = i * 8192 + tid * 16;           // linear LDS byte offset
        const int row = off >> 7;                      // 0..255
        const int sc  = ((off >> 4) & 7) ^ (row & 7);  // involution
        const int goff = row * 512 + ktb + sc * 16;    // global row stride 512B
        gld16(gA + goff, lA + off);
        gld16(gB + goff, lB + off);
    }
}

__device__ __forceinline__ void compute_kt(const char* Asb, const char* Bsb,
                                           f32x4 (&acc)[8][4],
                                           int wr, int wc, int r16, int hi)
{
    #pragma unroll
    for (int kk = 0; kk < 2; ++kk) {
        short8 b[4];
        #pragma unroll
        for (int ni = 0; ni < 4; ++ni) {
            const int row = wc * 64 + ni * 16 + r16;
            const int c16 = (kk * 4 + hi) ^ (row & 7);
            b[ni] = *(const short8*)(Bsb + row * 128 + c16 * 16);
        }
        #pragma unroll
        for (int mi = 0; mi < 8; ++mi) {
            const int row = wr * 128 + mi * 16 + r16;
            const int c16 = (kk * 4 + hi) ^ (row & 7);
            const short8 a = *(const short8*)(Asb + row * 128 + c16 * 16);
            #pragma unroll
            for (int ni = 0; ni < 4; ++ni)
                acc[mi][ni] = __builtin_amdgcn_mfma_f32_16x16x32_bf16(
                    a, b[ni], acc[mi][ni], 0, 0, 0);
        }
    }
}

#define WAITVM(n) do { \
    asm volatile("s_waitcnt vmcnt(" #n ")" ::: "memory"); \
    __builtin_amdgcn_sched_barrier(0); \
} while (0)

// ---------------- fused GEMM + exp + column-sum + diagonal ----------------
__global__ __launch_bounds__(512, 1) void gemm_kernel(const unsigned short* __restrict__ tnb,
                                                      const unsigned short* __restrict__ cnb,
                                                      const float* __restrict__ alphaP,
                                                      const float* __restrict__ betaP,
                                                      float* __restrict__ total,
                                                      float* __restrict__ pos)
{
    __shared__ __align__(16) char As[2][BM * BK * 2];   // 2 x 32 KiB
    __shared__ __align__(16) char Bs[2][BN * BK * 2];   // 2 x 32 KiB  -> 128 KiB total

    const int tid = threadIdx.x;
    const int l = tid & 63;
    const int w = tid >> 6;            // 0..7
    const int wr = w >> 2, wc = w & 3; // 2M x 4N
    const int r16 = l & 15, hi = l >> 4;

    // T1: XCD-aware bijective swizzle; nwg=1024, 8 XCDs -> chunks of 128.
    // Each XCD owns bm in [xcd*16, xcd*16+16) x all 8 bn: B fully L2-resident,
    // 16 A-panels (2 MiB) L2-resident.
    const int bid = blockIdx.x;
    const int tile = (bid & 7) * 128 + (bid >> 3);
    const int bm = tile >> 3;          // 0..127
    const int bn = tile & 7;           // 0..7

    const char* gA = (const char*)tnb + (size_t)bm * BM * 512;
    const char* gB = (const char*)cnb + (size_t)bn * BN * 512;

    f32x4 acc[8][4] = {};

    // prologue: stage kt0 -> buf0, kt1 -> buf1 (16 loads/thread in flight)
    stage_kt(gA, gB, As[0], Bs[0], 0 * 128, tid);
    stage_kt(gA, gB, As[1], Bs[1], 1 * 128, tid);
    WAITVM(8);                                   // kt0 landed
    __builtin_amdgcn_s_barrier();

    compute_kt(As[0], Bs[0], acc, wr, wc, r16, hi);   // kt0 (kt1 in flight)
    __builtin_amdgcn_s_barrier();                     // buf0 free
    stage_kt(gA, gB, As[0], Bs[0], 2 * 128, tid);     // kt2 -> buf0
    WAITVM(8);                                        // kt1 landed
    __builtin_amdgcn_s_barrier();

    compute_kt(As[1], Bs[1], acc, wr, wc, r16, hi);   // kt1 (kt2 in flight)
    __builtin_amdgcn_s_barrier();                     // buf1 free
    stage_kt(gA, gB, As[1], Bs[1], 3 * 128, tid);     // kt3 -> buf1
    WAITVM(8);                                        // kt2 landed
    __builtin_amdgcn_s_barrier();

    compute_kt(As[0], Bs[0], acc, wr, wc, r16, hi);   // kt2 (kt3 in flight)
    WAITVM(0);                                        // kt3 landed
    __builtin_amdgcn_s_barrier();

    compute_kt(As[1], Bs[1], acc, wr, wc, r16, hi);   // kt3

    // ---- epilogue: exp, column sums, diagonal ----
    __builtin_amdgcn_s_barrier();                // all ds_reads of As/Bs done
    float* colsum = (float*)As;                  // alias freed LDS (256 floats)
    if (tid < BN) colsum[tid] = 0.0f;
    __builtin_amdgcn_s_barrier();

    const float alpha = *alphaP;
    const float beta  = *betaP;

    #pragma unroll
    for (int ni = 0; ni < 4; ++ni) {
        const int colg = bn * BN + wc * 64 + ni * 16 + r16;   // C/D: col = lane&15
        float csum = 0.f;
        #pragma unroll
        for (int mi = 0; mi < 8; ++mi) {
            const int rowbase = bm * BM + wr * 128 + mi * 16 + hi * 4;  // row=(l>>4)*4+r
            #pragma unroll
            for (int r = 0; r < 4; ++r) {
                const float e = __expf(alpha * acc[mi][ni][r] + beta);
                csum += e;
                if (((rowbase + r) >> 4) == colg)     // positive pair
                    atomicAdd(pos + colg, e);
            }
        }
        csum += __shfl_xor(csum, 16);
        csum += __shfl_xor(csum, 32);
        if (hi == 0) atomicAdd(&colsum[wc * 64 + ni * 16 + r16], csum);
    }
    __syncthreads();
    if (tid < BN) atomicAdd(total + bn * BN + tid, colsum[tid]);
}

// ---------------- finalize: loss = mean(log(tot-pos) - log(pos)) ----------
__global__ __launch_bounds__(256) void finalize_kernel(const float* __restrict__ total,
                                                       const float* __restrict__ pos,
                                                       float* __restrict__ out)
{
    const int tid = threadIdx.x;
    float s = 0.f;
    for (int i = tid; i < N_SPK; i += 256) {
        const float p = pos[i];
        const float t = total[i];
        s += logf(t - p) - logf(p);
    }
    #pragma unroll
    for (int d = 1; d < 64; d <<= 1) s += __shfl_xor(s, d);
    __shared__ float wsum[4];
    if ((tid & 63) == 0) wsum[tid >> 6] = s;
    __syncthreads();
    if (tid == 0) out[0] = (wsum[0] + wsum[1] + wsum[2] + wsum[3]) * (1.0f / (float)N_SPK);
}

extern "C" void kernel_launch(void* const* d_in, const int* in_sizes, int n_in,
                              void* d_out, int out_size, void* d_ws, size_t ws_size,
                              hipStream_t stream)
{
    const float* emb    = (const float*)d_in[0];
    const float* alphaP = (const float*)d_in[2];
    const float* betaP  = (const float*)d_in[3];
    float* out = (float*)d_out;

    char* ws = (char*)d_ws;
    unsigned short* tn = (unsigned short*)ws;                       // 16 MiB
    unsigned short* cn = (unsigned short*)(ws + 16777216);          // 1 MiB
    float* total       = (float*)(ws + 16777216 + 1048576);         // 2048 f32
    float* pos         = total + N_SPK;                             // 2048 f32

    hipMemsetAsync(total, 0, 2 * N_SPK * sizeof(float), stream);

    hipLaunchKernelGGL(prep_kernel, dim3((M_ROWS + N_SPK) / 4), dim3(256), 0, stream,
                       emb, tn, cn);
    hipLaunchKernelGGL(gemm_kernel, dim3(M_ROWS / BM * (N_SPK / BN)), dim3(512), 0, stream,
                       tn, cn, alphaP, betaP, total, pos);
    hipLaunchKernelGGL(finalize_kernel, dim3(1), dim3(256), 0, stream,
                       total, pos, out);
}

// Round 3
// 157.768 us; speedup vs baseline: 1.0782x; 1.0107x over previous
//
#include <hip/hip_runtime.h>
#include <hip/hip_bf16.h>
#include <stdint.h>

#define N_SPK 2048
#define UU 32
#define DD 256
#define HALF_U 16
#define M_ROWS (N_SPK * HALF_U)   // 32768 test rows

#define BM 256
#define BN 256
#define BK 64

typedef __attribute__((ext_vector_type(8))) short short8;   // 8 bf16 = 4 VGPRs
typedef __attribute__((ext_vector_type(4))) float f32x4;

typedef const __attribute__((address_space(1))) void ga_void;
typedef __attribute__((address_space(3))) void ls_void;

__device__ __forceinline__ void gld16(const void* g, void* l) {
    __builtin_amdgcn_global_load_lds((ga_void*)(uintptr_t)g,
                                     (ls_void*)(uintptr_t)l, 16, 0, 0);
}

__device__ __forceinline__ unsigned short f2bf(float x) {
    union { float f; unsigned u; } c; c.f = x;
    unsigned r = c.u + 0x7fffu + ((c.u >> 16) & 1u);  // RNE, no NaN inputs
    return (unsigned short)(r >> 16);
}

#define WAITVM(n) do { \
    asm volatile("s_waitcnt vmcnt(" #n ")" ::: "memory"); \
    __builtin_amdgcn_sched_barrier(0); \
} while (0)

#define WAITLGKM0 do { \
    asm volatile("s_waitcnt lgkmcnt(0)" ::: "memory"); \
    __builtin_amdgcn_sched_barrier(0); \
} while (0)

// ---------------- prep: centroids + normalization -> bf16 ----------------
// one wave per output row; block 0 also zero-inits total/pos (replaces memset)
__global__ __launch_bounds__(256) void prep_kernel(const float* __restrict__ emb,
                                                   unsigned short* __restrict__ tn,
                                                   unsigned short* __restrict__ cn,
                                                   float* __restrict__ zbuf)
{
    if (blockIdx.x == 0) {
        #pragma unroll
        for (int i = 0; i < 16; ++i) zbuf[threadIdx.x + 256 * i] = 0.0f;   // 4096 floats
    }

    const int w = threadIdx.x >> 6;
    const int l = threadIdx.x & 63;
    const int task = blockIdx.x * 4 + w;

    float4 v;
    if (task < M_ROWS) {
        const int m = task >> 4;
        const int t = task & 15;
        const size_t grow = (size_t)m * UU + HALF_U + t;
        v = *(const float4*)(emb + grow * DD + 4 * l);
    } else {
        const int n = task - M_ROWS;
        float ax = 0.f, ay = 0.f, az = 0.f, aw = 0.f;
        const float* base = emb + (size_t)n * UU * DD + 4 * l;
        #pragma unroll
        for (int j = 0; j < HALF_U; ++j) {
            float4 e = *(const float4*)(base + j * DD);
            ax += e.x; ay += e.y; az += e.z; aw += e.w;
        }
        const float inv = 1.0f / 16.0f;
        v = make_float4(ax * inv, ay * inv, az * inv, aw * inv);
    }
    float ss = v.x * v.x + v.y * v.y + v.z * v.z + v.w * v.w;
    #pragma unroll
    for (int d = 1; d < 64; d <<= 1) ss += __shfl_xor(ss, d);
    const float sc = 1.0f / fmaxf(sqrtf(ss), 1e-8f);

    ushort4 o;
    o.x = f2bf(v.x * sc); o.y = f2bf(v.y * sc);
    o.z = f2bf(v.z * sc); o.w = f2bf(v.w * sc);
    unsigned short* dst = (task < M_ROWS)
        ? (tn + (size_t)task * DD + 4 * l)
        : (cn + (size_t)(task - M_ROWS) * DD + 4 * l);
    *(ushort4*)dst = o;
}

// ---------------- fused GEMM + exp + column-sum + diagonal ----------------
// 8-phase schedule (T3+T4+T5+T2+T1), 256^2 tile, 8 waves (2M x 4N), K=256.
// LDS: 4 slots of 32 KiB = [A-half 16K][B-half 16K]; slot(kt,h) = (2kt+h)&3.
// Half-tile = 128 rows x 64 cols of one matrix; XOR-swizzled both sides.
__global__ __launch_bounds__(512, 2) void gemm_kernel(const unsigned short* __restrict__ tnb,
                                                      const unsigned short* __restrict__ cnb,
                                                      const float* __restrict__ alphaP,
                                                      const float* __restrict__ betaP,
                                                      float* __restrict__ total,
                                                      float* __restrict__ pos)
{
    __shared__ __align__(16) char S[4][32768];

    const int tid = threadIdx.x;
    const int l = tid & 63;
    const int w = tid >> 6;            // 0..7
    const int wr = w >> 2, wc = w & 3; // 2M x 4N; per-wave out 128x64
    const int r16 = l & 15, hi = l >> 4;

    const float alpha = *alphaP;
    const float beta  = *betaP;

    // T1: XCD-aware bijective swizzle (nwg=1024 % 8 == 0)
    const int bid = blockIdx.x;
    const int tile = (bid & 7) * 128 + (bid >> 3);
    const int bm = tile >> 3;          // 0..127
    const int bn = tile & 7;           // 0..7

    const char* gA = (const char*)tnb + (size_t)bm * BM * 512;   // row stride 512 B
    const char* gB = (const char*)cnb + (size_t)bn * BN * 512;

    // stage one 16 KiB half (matrix mat, half h) of K-tile kt: 2 loads/thread
    auto stage_unit = [&](int kt, int u) {   // u: 0=A0,1=B0,2=A1,3=B1
        const int h = u >> 1;
        const int mat = u & 1;
        char* slot = S[(2 * kt + h) & 3] + mat * 16384;
        const char* g = mat ? gB : gA;
        #pragma unroll
        for (int i = 0; i < 2; ++i) {
            const int off = i * 8192 + tid * 16;       // linear LDS byte offset
            const int row = off >> 7;                  // local row 0..127
            const int sc  = ((off >> 4) & 7) ^ (row & 7);
            const int goff = (h * 128 + row) * 512 + kt * 128 + sc * 16;
            gld16(g + goff, slot + off);
        }
    };

    f32x4 acc[8][4] = {};

    // prologue: kt0 + kt1 fully staged (16 loads/thread)
    #pragma unroll
    for (int u = 0; u < 4; ++u) stage_unit(0, u);
    #pragma unroll
    for (int u = 0; u < 4; ++u) stage_unit(1, u);
    WAITVM(8);                                    // kt0's 8 landed
    __builtin_amdgcn_s_barrier();

    #pragma unroll
    for (int kt = 0; kt < 4; ++kt) {
        const char* As = S[(2 * kt + wr) & 3];                  // this wave's A-half
        const char* Bs = S[(2 * kt + (wc >> 1)) & 3] + 16384;   // this wave's B-half
        short8 b[4][2];
        #pragma unroll
        for (int p = 0; p < 4; ++p) {             // phase = mi-pair {2p, 2p+1}
            short8 a[2][2];
            if (p == 0) {
                #pragma unroll
                for (int ni = 0; ni < 4; ++ni)
                    #pragma unroll
                    for (int kk = 0; kk < 2; ++kk) {
                        const int row = wc * 64 + ni * 16 + r16;
                        const int c16 = (kk * 4 + hi) ^ (row & 7);
                        b[ni][kk] = *(const short8*)(Bs + (row & 127) * 128 + c16 * 16);
                    }
            }
            #pragma unroll
            for (int m2 = 0; m2 < 2; ++m2)
                #pragma unroll
                for (int kk = 0; kk < 2; ++kk) {
                    const int mi = p * 2 + m2;
                    const int lrow = mi * 16 + r16;            // local row in half
                    const int c16 = (kk * 4 + hi) ^ (lrow & 7);
                    a[m2][kk] = *(const short8*)(As + lrow * 128 + c16 * 16);
                }
            // front-loaded prefetch of kt+1 (kt0 prefetched kt1 in prologue)
            if (kt == 1 || kt == 2) {
                if (p == 0) { stage_unit(kt + 1, 0); stage_unit(kt + 1, 1); }
                if (p == 1) { stage_unit(kt + 1, 2); stage_unit(kt + 1, 3); }
            }
            __builtin_amdgcn_s_barrier();
            WAITLGKM0;
            __builtin_amdgcn_s_setprio(1);
            #pragma unroll
            for (int kk = 0; kk < 2; ++kk)
                #pragma unroll
                for (int m2 = 0; m2 < 2; ++m2)
                    #pragma unroll
                    for (int ni = 0; ni < 4; ++ni)
                        acc[p * 2 + m2][ni] = __builtin_amdgcn_mfma_f32_16x16x32_bf16(
                            a[m2][kk], b[ni][kk], acc[p * 2 + m2][ni], 0, 0, 0);
            __builtin_amdgcn_s_setprio(0);
            __builtin_amdgcn_s_barrier();
        }
        if (kt < 3) {
            // next kt's 8 loads are the only outstanding ops: exact drain
            WAITVM(0);
            __builtin_amdgcn_s_barrier();
        }
    }

    // ---- epilogue: exp, column sums, diagonal ----
    float* colsum = (float*)S;                   // alias freed LDS
    __syncthreads();
    if (tid < BN) colsum[tid] = 0.0f;
    __syncthreads();

    #pragma unroll
    for (int ni = 0; ni < 4; ++ni) {
        const int colg = bn * BN + wc * 64 + ni * 16 + r16;   // C/D: col = lane&15
        float csum = 0.f;
        #pragma unroll
        for (int mi = 0; mi < 8; ++mi) {
            const int rowbase = bm * BM + wr * 128 + mi * 16 + hi * 4;  // row=(l>>4)*4+r
            #pragma unroll
            for (int r = 0; r < 4; ++r) {
                const float e = __expf(alpha * acc[mi][ni][r] + beta);
                csum += e;
                if (((rowbase + r) >> 4) == colg)     // positive pair
                    atomicAdd(pos + colg, e);
            }
        }
        csum += __shfl_xor(csum, 16);
        csum += __shfl_xor(csum, 32);
        if (hi == 0) atomicAdd(&colsum[wc * 64 + ni * 16 + r16], csum);
    }
    __syncthreads();
    if (tid < BN) atomicAdd(total + bn * BN + tid, colsum[tid]);
}

// ---------------- finalize: loss = mean(log(tot-pos) - log(pos)) ----------
__global__ __launch_bounds__(256) void finalize_kernel(const float* __restrict__ total,
                                                       const float* __restrict__ pos,
                                                       float* __restrict__ out)
{
    const int tid = threadIdx.x;
    float s = 0.f;
    for (int i = tid; i < N_SPK; i += 256) {
        const float p = pos[i];
        const float t = total[i];
        s += logf(t - p) - logf(p);
    }
    #pragma unroll
    for (int d = 1; d < 64; d <<= 1) s += __shfl_xor(s, d);
    __shared__ float wsum[4];
    if ((tid & 63) == 0) wsum[tid >> 6] = s;
    __syncthreads();
    if (tid == 0) out[0] = (wsum[0] + wsum[1] + wsum[2] + wsum[3]) * (1.0f / (float)N_SPK);
}

extern "C" void kernel_launch(void* const* d_in, const int* in_sizes, int n_in,
                              void* d_out, int out_size, void* d_ws, size_t ws_size,
                              hipStream_t stream)
{
    const float* emb    = (const float*)d_in[0];
    const float* alphaP = (const float*)d_in[2];
    const float* betaP  = (const float*)d_in[3];
    float* out = (float*)d_out;

    char* ws = (char*)d_ws;
    unsigned short* tn = (unsigned short*)ws;                       // 16 MiB
    unsigned short* cn = (unsigned short*)(ws + 16777216);          // 1 MiB
    float* total       = (float*)(ws + 16777216 + 1048576);         // 2048 f32
    float* pos         = total + N_SPK;                             // 2048 f32

    hipLaunchKernelGGL(prep_kernel, dim3((M_ROWS + N_SPK) / 4), dim3(256), 0, stream,
                       emb, tn, cn, total /* zeroes total+pos (4096 f32) */);
    hipLaunchKernelGGL(gemm_kernel, dim3(M_ROWS / BM * (N_SPK / BN)), dim3(512), 0, stream,
                       tn, cn, alphaP, betaP, total, pos);
    hipLaunchKernelGGL(finalize_kernel, dim3(1), dim3(256), 0, stream,
                       total, pos, out);
}

// Round 4
// 155.879 us; speedup vs baseline: 1.0912x; 1.0121x over previous
//
#include <hip/hip_runtime.h>
#include <hip/hip_bf16.h>
#include <stdint.h>

#define N_SPK 2048
#define UU 32
#define DD 256
#define HALF_U 16
#define M_ROWS (N_SPK * HALF_U)   // 32768 test rows

#define BM 256
#define BN 256
#define BK 64

typedef __attribute__((ext_vector_type(8))) short short8;   // 8 bf16 = 4 VGPRs
typedef __attribute__((ext_vector_type(4))) float f32x4;

typedef const __attribute__((address_space(1))) void ga_void;
typedef __attribute__((address_space(3))) void ls_void;

__device__ __forceinline__ void gld16(const void* g, void* l) {
    __builtin_amdgcn_global_load_lds((ga_void*)(uintptr_t)g,
                                     (ls_void*)(uintptr_t)l, 16, 0, 0);
}

__device__ __forceinline__ unsigned short f2bf(float x) {
    union { float f; unsigned u; } c; c.f = x;
    unsigned r = c.u + 0x7fffu + ((c.u >> 16) & 1u);  // RNE, no NaN inputs
    return (unsigned short)(r >> 16);
}

#define WAITVM(n) do { \
    asm volatile("s_waitcnt vmcnt(" #n ")" ::: "memory"); \
    __builtin_amdgcn_sched_barrier(0); \
} while (0)

#define WAITLGKM0 do { \
    asm volatile("s_waitcnt lgkmcnt(0)" ::: "memory"); \
    __builtin_amdgcn_sched_barrier(0); \
} while (0)

// ---------------- prep: centroids + normalization -> bf16 ----------------
__global__ __launch_bounds__(256) void prep_kernel(const float* __restrict__ emb,
                                                   unsigned short* __restrict__ tn,
                                                   unsigned short* __restrict__ cn,
                                                   float* __restrict__ zbuf)
{
    if (blockIdx.x == 0) {
        #pragma unroll
        for (int i = 0; i < 16; ++i) zbuf[threadIdx.x + 256 * i] = 0.0f;   // 4096 floats
    }

    const int w = threadIdx.x >> 6;
    const int l = threadIdx.x & 63;
    const int task = blockIdx.x * 4 + w;

    float4 v;
    if (task < M_ROWS) {
        const int m = task >> 4;
        const int t = task & 15;
        const size_t grow = (size_t)m * UU + HALF_U + t;
        v = *(const float4*)(emb + grow * DD + 4 * l);
    } else {
        const int n = task - M_ROWS;
        float ax = 0.f, ay = 0.f, az = 0.f, aw = 0.f;
        const float* base = emb + (size_t)n * UU * DD + 4 * l;
        #pragma unroll
        for (int j = 0; j < HALF_U; ++j) {
            float4 e = *(const float4*)(base + j * DD);
            ax += e.x; ay += e.y; az += e.z; aw += e.w;
        }
        const float inv = 1.0f / 16.0f;
        v = make_float4(ax * inv, ay * inv, az * inv, aw * inv);
    }
    float ss = v.x * v.x + v.y * v.y + v.z * v.z + v.w * v.w;
    #pragma unroll
    for (int d = 1; d < 64; d <<= 1) ss += __shfl_xor(ss, d);
    const float sc = 1.0f / fmaxf(sqrtf(ss), 1e-8f);

    ushort4 o;
    o.x = f2bf(v.x * sc); o.y = f2bf(v.y * sc);
    o.z = f2bf(v.z * sc); o.w = f2bf(v.w * sc);
    unsigned short* dst = (task < M_ROWS)
        ? (tn + (size_t)task * DD + 4 * l)
        : (cn + (size_t)(task - M_ROWS) * DD + 4 * l);
    *(ushort4*)dst = o;
}

// ---------------- persistent fused GEMM: 4 tiles per block ----------------
// grid 256 (1 block/CU), block 512 (8 waves, 2M x 4N). Each block: fixed bm,
// tiles bn = bn0..bn0+3 as ONE continuous 16-step kt pipeline (j = t*4 + kt).
// LDS: 4 slots x 32 KiB rotating mod-2-kt; slot(j,h) = (2j+h)&3. XOR swizzle
// both sides (global source pre-swizzled, ds_read swizzled; LDS dest linear).
__global__ __launch_bounds__(512, 2) void gemm_kernel(const unsigned short* __restrict__ tnb,
                                                      const unsigned short* __restrict__ cnb,
                                                      const float* __restrict__ alphaP,
                                                      const float* __restrict__ betaP,
                                                      float* __restrict__ total,
                                                      float* __restrict__ pos)
{
    __shared__ __align__(16) char S[4][32768];
    __shared__ float csum[BN];

    const int tid = threadIdx.x;
    const int l = tid & 63;
    const int w = tid >> 6;            // 0..7
    const int wr = w >> 2, wc = w & 3; // per-wave out 128x64
    const int r16 = l & 15, hi = l >> 4;

    const float alpha = *alphaP;
    const float beta  = *betaP;

    // XCD-local mapping: xcd = bid&7 (HW round-robin), 32 blocks/XCD cover
    // bm in [xcd*16, xcd*16+16) x bn 0..7  (2 blocks per bm: bn0 = 0 or 4)
    const int c = blockIdx.x;          // 0..255
    const int xcd = c & 7, slot = c >> 3;
    const int bm = xcd * 16 + (slot >> 1);   // 0..127
    const int bn0 = (slot & 1) * 4;          // 0 or 4

    const char* gA = (const char*)tnb + (size_t)bm * BM * 512;   // row stride 512 B

    // stage half h (0/1) of global kt-step jj: A-half + B-half (4 gld/thread)
    auto stage_half = [&](int jj, int h) {
        const int kt = jj & 3;
        const int bn = bn0 + (jj >> 2);
        char* slotp = S[(2 * jj + h) & 3];
        const char* gB = (const char*)cnb + (size_t)bn * BN * 512;
        #pragma unroll
        for (int i = 0; i < 2; ++i) {
            const int off = i * 8192 + tid * 16;       // linear LDS byte offset
            const int row = off >> 7;                  // local row 0..127
            const int sc  = ((off >> 4) & 7) ^ (row & 7);
            const int goff = (h * 128 + row) * 512 + kt * 128 + sc * 16;
            gld16(gA + goff, slotp + off);
            gld16(gB + goff, slotp + 16384 + off);
        }
    };

    f32x4 acc[8][4] = {};

    // prologue: j0 + j1 fully staged (16 loads/thread in flight)
    stage_half(0, 0); stage_half(0, 1);
    stage_half(1, 0); stage_half(1, 1);
    WAITVM(8);                                    // j0's 8 landed (j1's in flight)
    __builtin_amdgcn_s_barrier();

    for (int j = 0; j < 16; ++j) {
        const char* As = S[(2 * j + wr) & 3];                  // this wave's A-half
        const char* Bs = S[(2 * j + (wc >> 1)) & 3] + 16384;   // this wave's B-half
        short8 b[4][2];
        #pragma unroll
        for (int p = 0; p < 4; ++p) {             // phase = mi-pair {2p, 2p+1}
            short8 a[2][2];
            if (p == 0) {
                #pragma unroll
                for (int ni = 0; ni < 4; ++ni)
                    #pragma unroll
                    for (int kk = 0; kk < 2; ++kk) {
                        const int row = wc * 64 + ni * 16 + r16;
                        const int c16 = (kk * 4 + hi) ^ (row & 7);
                        b[ni][kk] = *(const short8*)(Bs + (row & 127) * 128 + c16 * 16);
                    }
            }
            #pragma unroll
            for (int m2 = 0; m2 < 2; ++m2)
                #pragma unroll
                for (int kk = 0; kk < 2; ++kk) {
                    const int mi = p * 2 + m2;
                    const int lrow = mi * 16 + r16;            // local row in half
                    const int c16 = (kk * 4 + hi) ^ (lrow & 7);
                    a[m2][kk] = *(const short8*)(As + lrow * 128 + c16 * 16);
                }
            if (j < 15) {                          // prefetch j+1 (front-loaded)
                if (p == 0) stage_half(j + 1, 0);
                if (p == 1) stage_half(j + 1, 1);
            }
            __builtin_amdgcn_s_barrier();
            WAITLGKM0;
            __builtin_amdgcn_s_setprio(1);
            #pragma unroll
            for (int kk = 0; kk < 2; ++kk)
                #pragma unroll
                for (int m2 = 0; m2 < 2; ++m2)
                    #pragma unroll
                    for (int ni = 0; ni < 4; ++ni)
                        acc[p * 2 + m2][ni] = __builtin_amdgcn_mfma_f32_16x16x32_bf16(
                            a[m2][kk], b[ni][kk], acc[p * 2 + m2][ni], 0, 0, 0);
            __builtin_amdgcn_s_setprio(0);
            __builtin_amdgcn_s_barrier();
        }

        if ((j & 3) == 3) {
            // ---- per-tile epilogue (staging for next tile stays in flight) ----
            const int bn = bn0 + (j >> 2);
            const bool diag = ((bm >> 4) == bn);
            if (tid < BN) csum[tid] = 0.0f;
            __builtin_amdgcn_s_barrier();
            #pragma unroll
            for (int ni = 0; ni < 4; ++ni) {
                const int colg = bn * BN + wc * 64 + ni * 16 + r16;  // col = lane&15
                float cs = 0.f;
                #pragma unroll
                for (int mi = 0; mi < 8; ++mi) {
                    const int rowbase = bm * BM + wr * 128 + mi * 16 + hi * 4;
                    #pragma unroll
                    for (int r = 0; r < 4; ++r) {
                        const float e = __expf(alpha * acc[mi][ni][r] + beta);
                        cs += e;
                        if (diag && ((rowbase + r) >> 4) == colg)    // positive pair
                            atomicAdd(pos + colg, e);
                    }
                    acc[mi][ni] = (f32x4){0.f, 0.f, 0.f, 0.f};       // re-zero for next tile
                }
                cs += __shfl_xor(cs, 16);
                cs += __shfl_xor(cs, 32);
                if (hi == 0) atomicAdd(&csum[wc * 64 + ni * 16 + r16], cs);
            }
            __builtin_amdgcn_s_barrier();
            if (tid < BN) atomicAdd(total + bn * BN + tid, csum[tid]);
            __builtin_amdgcn_s_barrier();
        }

        if (j < 15) {
            WAITVM(0);                            // j+1's 8 landed (issued p0/p1 of j)
            __builtin_amdgcn_s_barrier();
        }
    }
}

// ---------------- finalize: loss = mean(log(tot-pos) - log(pos)) ----------
__global__ __launch_bounds__(256) void finalize_kernel(const float* __restrict__ total,
                                                       const float* __restrict__ pos,
                                                       float* __restrict__ out)
{
    const int tid = threadIdx.x;
    float s = 0.f;
    for (int i = tid; i < N_SPK; i += 256) {
        const float p = pos[i];
        const float t = total[i];
        s += logf(t - p) - logf(p);
    }
    #pragma unroll
    for (int d = 1; d < 64; d <<= 1) s += __shfl_xor(s, d);
    __shared__ float wsum[4];
    if ((tid & 63) == 0) wsum[tid >> 6] = s;
    __syncthreads();
    if (tid == 0) out[0] = (wsum[0] + wsum[1] + wsum[2] + wsum[3]) * (1.0f / (float)N_SPK);
}

extern "C" void kernel_launch(void* const* d_in, const int* in_sizes, int n_in,
                              void* d_out, int out_size, void* d_ws, size_t ws_size,
                              hipStream_t stream)
{
    const float* emb    = (const float*)d_in[0];
    const float* alphaP = (const float*)d_in[2];
    const float* betaP  = (const float*)d_in[3];
    float* out = (float*)d_out;

    char* ws = (char*)d_ws;
    unsigned short* tn = (unsigned short*)ws;                       // 16 MiB
    unsigned short* cn = (unsigned short*)(ws + 16777216);          // 1 MiB
    float* total       = (float*)(ws + 16777216 + 1048576);         // 2048 f32
    float* pos         = total + N_SPK;                             // 2048 f32

    hipLaunchKernelGGL(prep_kernel, dim3((M_ROWS + N_SPK) / 4), dim3(256), 0, stream,
                       emb, tn, cn, total /* zeroes total+pos (4096 f32) */);
    hipLaunchKernelGGL(gemm_kernel, dim3(256), dim3(512), 0, stream,
                       tn, cn, alphaP, betaP, total, pos);
    hipLaunchKernelGGL(finalize_kernel, dim3(1), dim3(256), 0, stream,
                       total, pos, out);
}